// Round 1
// 991.523 us; speedup vs baseline: 1.5987x; 1.5987x over previous
//
#include <hip/hip_runtime.h>

#define HD 64
#define KP 16            // timesteps per phase (one workgroup barrier per phase)
#define NS 32            // ring slots = 2 phases (double buffer)
#define L2E 1.4426950408889634f

typedef _Float16 v2h __attribute__((ext_vector_type(2)));
typedef _Float16 h8  __attribute__((ext_vector_type(8)));

__device__ __forceinline__ float fexp2(float x) { return __builtin_amdgcn_exp2f(x); }
__device__ __forceinline__ float frcp(float x)  { return __builtin_amdgcn_rcpf(x); }
__device__ __forceinline__ float ftanh_fast(float x) {
    return 1.f - 2.f * frcp(fexp2(2.f * L2E * x) + 1.f);
}
__device__ __forceinline__ float fsig(float x) {
    return frcp(fexp2(-L2E * x) + 1.f);
}

#if __has_builtin(__builtin_amdgcn_fdot2)
__device__ __forceinline__ float FDOT2(v2h a, v2h b, float c) {
    return __builtin_amdgcn_fdot2(a, b, c, false);
}
#else
__device__ __forceinline__ float FDOT2(v2h a, v2h b, float c) {
    return fmaf((float)a.x, (float)b.x, fmaf((float)a.y, (float)b.y, c));
}
#endif

// Load one 64-wide f32 weight row, convert to 32 packed f16 pairs (registers).
#define LOADROW(W, r, dst) do { \
    const float4* wp_ = (const float4*)((W) + (size_t)(r) * HD); \
    _Pragma("unroll") \
    for (int q = 0; q < 16; ++q) { \
        float4 v = wp_[q]; \
        dst[2*q]   = v2h{(_Float16)v.x, (_Float16)v.y}; \
        dst[2*q+1] = v2h{(_Float16)v.z, (_Float16)v.w}; \
    } } while (0)

// 4-gate 64-dot: 128 v_dot2_f32_f16, two accumulator chains per gate
// (chain depth 16 -> issue-bound, not latency-bound).
#define DOT4(HP) do { \
    _Pragma("unroll") \
    for (int q = 0; q < 8; ++q) { \
        h8 hv = (HP)[q]; \
        v2h p0 = {hv[0],hv[1]}, p1 = {hv[2],hv[3]}; \
        v2h p2 = {hv[4],hv[5]}, p3 = {hv[6],hv[7]}; \
        a00 = FDOT2(wg0[4*q+0], p0, a00); a01 = FDOT2(wg0[4*q+1], p1, a01); \
        a00 = FDOT2(wg0[4*q+2], p2, a00); a01 = FDOT2(wg0[4*q+3], p3, a01); \
        a10 = FDOT2(wg1[4*q+0], p0, a10); a11 = FDOT2(wg1[4*q+1], p1, a11); \
        a10 = FDOT2(wg1[4*q+2], p2, a10); a11 = FDOT2(wg1[4*q+3], p3, a11); \
        a20 = FDOT2(wg2[4*q+0], p0, a20); a21 = FDOT2(wg2[4*q+1], p1, a21); \
        a20 = FDOT2(wg2[4*q+2], p2, a20); a21 = FDOT2(wg2[4*q+3], p3, a21); \
        a30 = FDOT2(wg3[4*q+0], p0, a30); a31 = FDOT2(wg3[4*q+1], p1, a31); \
        a30 = FDOT2(wg3[4*q+2], p2, a30); a31 = FDOT2(wg3[4*q+3], p3, a31); \
    } } while (0)

// Wave-local recurrence pipeline, one block per batch element, 5 waves:
//   w0 (A): layer-0 recurrence. lane = hidden unit, computes ALL 4 gates
//           (no cross-lane shuffles, no barrier: h roundtrips through LDS
//           within the same wave, DS pipe is in-order).
//   w1 (C): layer-1 recurrence, same layout. Also stores f32 h for the head.
//   w2/w3 (B): layer-1 input projection (2 gate rows per lane each), lag 1 phase.
//   w4 (D): output head, lag 3 phases, 16 lanes = 16 timesteps per phase.
// Workgroup barrier only once per KP=16 steps; all rings double-buffered
// by phase (NS = 2*KP slots), producer->consumer lag exactly 1 phase.
// Round-robin wave->SIMD puts the two recurrent waves on different SIMDs.
__launch_bounds__(320, 2)
__global__ void lstm2_kernel(const float* __restrict__ x,     // [B,T]
                             const float* __restrict__ h0in,  // [2,B,HD]
                             const float* __restrict__ c0in,  // [2,B,HD]
                             const float* __restrict__ Wih0,  // [4H,1]
                             const float* __restrict__ Whh0,  // [4H,HD]
                             const float* __restrict__ bih0,
                             const float* __restrict__ bhh0,
                             const float* __restrict__ Wih1,  // [4H,HD]
                             const float* __restrict__ Whh1,  // [4H,HD]
                             const float* __restrict__ bih1,
                             const float* __restrict__ bhh1,
                             const float* __restrict__ Wlin,  // [1,HD]
                             const float* __restrict__ blin,  // [1]
                             float* __restrict__ out,         // [B,T]
                             int B, int T)
{
    const int b    = blockIdx.x;
    const int tid  = threadIdx.x;
    const int wave = tid >> 6;
    const int lane = tid & 63;

    __shared__ __align__(16) _Float16 h0ring[NS][HD];        // layer-0 h (f16)
    __shared__ __align__(16) _Float16 h1ring[NS][HD];        // layer-1 h (f16)
    __shared__ __align__(16) float    h1f32[NS][HD + 4];     // layer-1 h (f32, head; +4 pad)
    __shared__ __align__(16) float    xpring[NS][4][HD];     // layer-1 xproj (f32)

    // ---- zero-init ALL LDS (launch-history independence), then barrier ----
    {
        _Float16* z0 = &h0ring[0][0];
        for (int i = tid; i < NS * HD; i += 320) z0[i] = (_Float16)0.f;
        _Float16* z1 = &h1ring[0][0];
        for (int i = tid; i < NS * HD; i += 320) z1[i] = (_Float16)0.f;
        float* z2 = &h1f32[0][0];
        for (int i = tid; i < NS * (HD + 4); i += 320) z2[i] = 0.f;
        float* z3 = &xpring[0][0][0];
        for (int i = tid; i < NS * 4 * HD; i += 320) z3[i] = 0.f;
    }
    __syncthreads();

    v2h wg0[32], wg1[32], wg2[32], wg3[32];   // per-wave weight rows (f16 pairs)
    float b0 = 0.f, b1 = 0.f, b2 = 0.f, b3 = 0.f;
    float wx0 = 0.f, wx1 = 0.f, wx2 = 0.f, wx3 = 0.f;
    float cst = 0.f;

    if (wave == 0) {                 // A: layer-0 recurrence
        LOADROW(Whh0, lane,        wg0);
        LOADROW(Whh0, 64 + lane,   wg1);
        LOADROW(Whh0, 128 + lane,  wg2);
        LOADROW(Whh0, 192 + lane,  wg3);
        b0 = bih0[lane]       + bhh0[lane];
        b1 = bih0[64 + lane]  + bhh0[64 + lane];
        b2 = bih0[128 + lane] + bhh0[128 + lane];
        b3 = bih0[192 + lane] + bhh0[192 + lane];
        wx0 = Wih0[lane];       wx1 = Wih0[64 + lane];
        wx2 = Wih0[128 + lane]; wx3 = Wih0[192 + lane];
        cst = c0in[b * HD + lane];
        h0ring[NS - 1][lane] = (_Float16)h0in[b * HD + lane];
    } else if (wave == 1) {          // C: layer-1 recurrence
        LOADROW(Whh1, lane,        wg0);
        LOADROW(Whh1, 64 + lane,   wg1);
        LOADROW(Whh1, 128 + lane,  wg2);
        LOADROW(Whh1, 192 + lane,  wg3);
        cst = c0in[B * HD + b * HD + lane];
        h1ring[NS - 1][lane] = (_Float16)h0in[B * HD + b * HD + lane];
    } else if (wave <= 3) {          // B0/B1: layer-1 input projection
        const int g0 = (wave - 2) * 2;
        LOADROW(Wih1, g0 * HD + lane,       wg0);
        LOADROW(Wih1, (g0 + 1) * HD + lane, wg1);
        b0 = bih1[g0 * HD + lane]       + bhh1[g0 * HD + lane];
        b1 = bih1[(g0 + 1) * HD + lane] + bhh1[(g0 + 1) * HD + lane];
    }
    const float blin0 = blin[0];
    __syncthreads();

    const int nphase = (T + KP - 1) / KP + 3;
    for (int p = 0; p < nphase; ++p) {
        if (wave == 0) {
            // -------- layer-0, steps [p*KP, p*KP+KP) --------
            const int t0 = p * KP;
            if (t0 < T) {
                #pragma unroll 1
                for (int k = 0; k < KP; ++k) {
                    const int t = t0 + k;
                    if (t >= T) break;
                    const float xv = x[(size_t)b * T + t];      // uniform scalar load
                    const h8* hp = (const h8*)h0ring[(t + NS - 1) & (NS - 1)];
                    float a00 = b0, a01 = 0.f, a10 = b1, a11 = 0.f;
                    float a20 = b2, a21 = 0.f, a30 = b3, a31 = 0.f;
                    DOT4(hp);
                    const float ai = fmaf(wx0, xv, a00 + a01);
                    const float af = fmaf(wx1, xv, a10 + a11);
                    const float ag = fmaf(wx2, xv, a20 + a21);
                    const float ao = fmaf(wx3, xv, a30 + a31);
                    const float iv = fsig(ai), fv = fsig(af);
                    const float gv = ftanh_fast(ag), ov = fsig(ao);
                    cst = fmaf(fv, cst, iv * gv);
                    const float h = ov * ftanh_fast(cst);
                    h0ring[t & (NS - 1)][lane] = (_Float16)h;   // same-wave roundtrip
                }
            }
        } else if (wave == 1) {
            // -------- layer-1 recurrence, lag 2 phases --------
            const int t0 = (p - 2) * KP;
            if (p >= 2 && t0 < T) {
                #pragma unroll 1
                for (int k = 0; k < KP; ++k) {
                    const int t = t0 + k;
                    if (t >= T) break;
                    const int s = t & (NS - 1);
                    const float x0 = xpring[s][0][lane];        // issued early,
                    const float x1 = xpring[s][1][lane];        // consumed after dots
                    const float x2 = xpring[s][2][lane];
                    const float x3 = xpring[s][3][lane];
                    const h8* hp = (const h8*)h1ring[(t + NS - 1) & (NS - 1)];
                    float a00 = 0.f, a01 = 0.f, a10 = 0.f, a11 = 0.f;
                    float a20 = 0.f, a21 = 0.f, a30 = 0.f, a31 = 0.f;
                    DOT4(hp);
                    const float ai = x0 + a00 + a01;
                    const float af = x1 + a10 + a11;
                    const float ag = x2 + a20 + a21;
                    const float ao = x3 + a30 + a31;
                    const float iv = fsig(ai), fv = fsig(af);
                    const float gv = ftanh_fast(ag), ov = fsig(ao);
                    cst = fmaf(fv, cst, iv * gv);
                    const float h = ov * ftanh_fast(cst);
                    h1ring[s][lane] = (_Float16)h;
                    h1f32[s][lane]  = h;                        // f32 h for output head
                }
            }
        } else if (wave <= 3) {
            // -------- layer-1 xproj, lag 1 phase --------
            const int t0 = (p - 1) * KP;
            if (p >= 1 && t0 < T) {
                const int g0 = (wave - 2) * 2;
                #pragma unroll 1
                for (int k = 0; k < KP; ++k) {
                    const int t = t0 + k;
                    if (t >= T) break;
                    const int s = t & (NS - 1);
                    const h8* hp = (const h8*)h0ring[s];
                    float a00 = b0, a01 = 0.f, a10 = b1, a11 = 0.f;
                    #pragma unroll
                    for (int q = 0; q < 8; ++q) {
                        h8 hv = hp[q];
                        v2h p0 = {hv[0],hv[1]}, p1 = {hv[2],hv[3]};
                        v2h p2 = {hv[4],hv[5]}, p3 = {hv[6],hv[7]};
                        a00 = FDOT2(wg0[4*q+0], p0, a00); a01 = FDOT2(wg0[4*q+1], p1, a01);
                        a00 = FDOT2(wg0[4*q+2], p2, a00); a01 = FDOT2(wg0[4*q+3], p3, a01);
                        a10 = FDOT2(wg1[4*q+0], p0, a10); a11 = FDOT2(wg1[4*q+1], p1, a11);
                        a10 = FDOT2(wg1[4*q+2], p2, a10); a11 = FDOT2(wg1[4*q+3], p3, a11);
                    }
                    xpring[s][g0][lane]     = a00 + a01;
                    xpring[s][g0 + 1][lane] = a10 + a11;
                }
            }
        } else {
            // -------- output head, lag 3 phases: lane k -> timestep t0+k --------
            const int t0 = (p - 3) * KP;
            if (p >= 3 && t0 < T && lane < KP) {
                const int t = t0 + lane;
                if (t < T) {
                    const float4* hv4 = (const float4*)h1f32[t & (NS - 1)];
                    const float4* wp  = (const float4*)Wlin;
                    float acc = blin0;
                    #pragma unroll
                    for (int q = 0; q < 16; ++q) {
                        const float4 hv = hv4[q];
                        const float4 wv = wp[q];
                        acc = fmaf(wv.x, hv.x, acc);
                        acc = fmaf(wv.y, hv.y, acc);
                        acc = fmaf(wv.z, hv.z, acc);
                        acc = fmaf(wv.w, hv.w, acc);
                    }
                    out[(size_t)b * T + t] = acc;
                }
            }
        }
        __syncthreads();   // one barrier per KP timesteps
    }
}

extern "C" void kernel_launch(void* const* d_in, const int* in_sizes, int n_in,
                              void* d_out, int out_size, void* d_ws, size_t ws_size,
                              hipStream_t stream)
{
    const float* x    = (const float*)d_in[0];
    const float* h0   = (const float*)d_in[1];
    const float* c0   = (const float*)d_in[2];
    const float* Wih0 = (const float*)d_in[3];
    const float* Whh0 = (const float*)d_in[4];
    const float* bih0 = (const float*)d_in[5];
    const float* bhh0 = (const float*)d_in[6];
    const float* Wih1 = (const float*)d_in[7];
    const float* Whh1 = (const float*)d_in[8];
    const float* bih1 = (const float*)d_in[9];
    const float* bhh1 = (const float*)d_in[10];
    const float* Wlin = (const float*)d_in[11];
    const float* blin = (const float*)d_in[12];
    float* out = (float*)d_out;

    const int B = in_sizes[1] / (2 * HD);   // h0 is [2,B,HD]
    const int T = in_sizes[0] / B;          // input is [B,T]

    lstm2_kernel<<<dim3(B), dim3(320), 0, stream>>>(
        x, h0, c0, Wih0, Whh0, bih0, bhh0,
        Wih1, Whh1, bih1, bhh1, Wlin, blin, out, B, T);
}

// Round 2
// 977.180 us; speedup vs baseline: 1.6222x; 1.0147x over previous
//
#include <hip/hip_runtime.h>

#define HD 64
#define KP 16            // timesteps per phase (one workgroup barrier per phase)
#define NS 32            // ring slots = 2 phases (double buffer)
#define L2E 1.4426950408889634f

typedef _Float16 v2h __attribute__((ext_vector_type(2)));
typedef _Float16 h8  __attribute__((ext_vector_type(8)));

__device__ __forceinline__ float fexp2(float x) { return __builtin_amdgcn_exp2f(x); }
__device__ __forceinline__ float frcp(float x)  { return __builtin_amdgcn_rcpf(x); }
__device__ __forceinline__ float ftanh_fast(float x) {
    return 1.f - 2.f * frcp(fexp2(2.f * L2E * x) + 1.f);
}
__device__ __forceinline__ float fsig(float x) {
    return frcp(fexp2(-L2E * x) + 1.f);
}

#if __has_builtin(__builtin_amdgcn_fdot2)
__device__ __forceinline__ float FDOT2(v2h a, v2h b, float c) {
    return __builtin_amdgcn_fdot2(a, b, c, false);
}
#else
__device__ __forceinline__ float FDOT2(v2h a, v2h b, float c) {
    return fmaf((float)a.x, (float)b.x, fmaf((float)a.y, (float)b.y, c));
}
#endif

// Load one 64-wide f32 weight row, convert to 32 packed f16 pairs (registers).
#define LOADROW(W, r, dst) do { \
    const float4* wp_ = (const float4*)((W) + (size_t)(r) * HD); \
    _Pragma("unroll") \
    for (int q = 0; q < 16; ++q) { \
        float4 v = wp_[q]; \
        dst[2*q]   = v2h{(_Float16)v.x, (_Float16)v.y}; \
        dst[2*q+1] = v2h{(_Float16)v.z, (_Float16)v.w}; \
    } } while (0)

// 4-gate 64-dot: 128 v_dot2_f32_f16, two accumulator chains per gate
// (chain depth 16 -> issue-bound, not latency-bound).
#define DOT4(HP) do { \
    _Pragma("unroll") \
    for (int q = 0; q < 8; ++q) { \
        h8 hv = (HP)[q]; \
        v2h p0 = {hv[0],hv[1]}, p1 = {hv[2],hv[3]}; \
        v2h p2 = {hv[4],hv[5]}, p3 = {hv[6],hv[7]}; \
        a00 = FDOT2(wg0[4*q+0], p0, a00); a01 = FDOT2(wg0[4*q+1], p1, a01); \
        a00 = FDOT2(wg0[4*q+2], p2, a00); a01 = FDOT2(wg0[4*q+3], p3, a01); \
        a10 = FDOT2(wg1[4*q+0], p0, a10); a11 = FDOT2(wg1[4*q+1], p1, a11); \
        a10 = FDOT2(wg1[4*q+2], p2, a10); a11 = FDOT2(wg1[4*q+3], p3, a11); \
        a20 = FDOT2(wg2[4*q+0], p0, a20); a21 = FDOT2(wg2[4*q+1], p1, a21); \
        a20 = FDOT2(wg2[4*q+2], p2, a20); a21 = FDOT2(wg2[4*q+3], p3, a21); \
        a30 = FDOT2(wg3[4*q+0], p0, a30); a31 = FDOT2(wg3[4*q+1], p1, a31); \
        a30 = FDOT2(wg3[4*q+2], p2, a30); a31 = FDOT2(wg3[4*q+3], p3, a31); \
    } } while (0)

// Wave-local recurrence pipeline, one block per batch element, 5 waves:
//   w0 (A): layer-0 recurrence (lane = hidden unit, all 4 gates in-lane).
//   w1 (C): layer-1 recurrence, same layout; also stores f32 h for the head.
//   w2/w3 (B): layer-1 input projection (2 gate rows per lane each), lag 1 phase.
//   w4 (D): output head, lag 3 phases.
// Workgroup barrier once per KP=16 steps; rings double-buffered by phase.
//
// __launch_bounds__(320, 1): we only ever need 1 block/CU (B == #CUs), so the
// register allocator may use up to 512 VGPRs. The R1 version's (320,2) bound
// gave VGPR_Count=124 < the 128 VGPRs of f16 weights alone -> weights spilled
// to scratch, reloaded every timestep (~32KB/wave/step through L1/L2) = the
// 2x gap vs the issue-rate model. Per-wave top-level loops (wave-uniform
// branches, equal barrier counts) keep each path's liveness independent.
__launch_bounds__(320, 1)
__global__ void lstm2_kernel(const float* __restrict__ x,     // [B,T]
                             const float* __restrict__ h0in,  // [2,B,HD]
                             const float* __restrict__ c0in,  // [2,B,HD]
                             const float* __restrict__ Wih0,  // [4H,1]
                             const float* __restrict__ Whh0,  // [4H,HD]
                             const float* __restrict__ bih0,
                             const float* __restrict__ bhh0,
                             const float* __restrict__ Wih1,  // [4H,HD]
                             const float* __restrict__ Whh1,  // [4H,HD]
                             const float* __restrict__ bih1,
                             const float* __restrict__ bhh1,
                             const float* __restrict__ Wlin,  // [1,HD]
                             const float* __restrict__ blin,  // [1]
                             float* __restrict__ out,         // [B,T]
                             int B, int T)
{
    const int b    = blockIdx.x;
    const int tid  = threadIdx.x;
    const int wave = tid >> 6;
    const int lane = tid & 63;

    __shared__ __align__(16) _Float16 h0ring[NS][HD];        // layer-0 h (f16)
    __shared__ __align__(16) _Float16 h1ring[NS][HD];        // layer-1 h (f16)
    __shared__ __align__(16) float    h1f32[NS][HD + 4];     // layer-1 h (f32, head; +4 pad)
    __shared__ __align__(16) float    xpring[NS][4][HD];     // layer-1 xproj (f32)

    // ---- zero-init ALL LDS (launch-history independence), then barrier ----
    {
        _Float16* z0 = &h0ring[0][0];
        for (int i = tid; i < NS * HD; i += 320) z0[i] = (_Float16)0.f;
        _Float16* z1 = &h1ring[0][0];
        for (int i = tid; i < NS * HD; i += 320) z1[i] = (_Float16)0.f;
        float* z2 = &h1f32[0][0];
        for (int i = tid; i < NS * (HD + 4); i += 320) z2[i] = 0.f;
        float* z3 = &xpring[0][0][0];
        for (int i = tid; i < NS * 4 * HD; i += 320) z3[i] = 0.f;
    }
    __syncthreads();

    const int nphase = (T + KP - 1) / KP + 3;

    if (wave == 0) {
        // ================= A: layer-0 recurrence =================
        v2h wg0[32], wg1[32], wg2[32], wg3[32];
        LOADROW(Whh0, lane,        wg0);
        LOADROW(Whh0, 64 + lane,   wg1);
        LOADROW(Whh0, 128 + lane,  wg2);
        LOADROW(Whh0, 192 + lane,  wg3);
        const float b0 = bih0[lane]       + bhh0[lane];
        const float b1 = bih0[64 + lane]  + bhh0[64 + lane];
        const float b2 = bih0[128 + lane] + bhh0[128 + lane];
        const float b3 = bih0[192 + lane] + bhh0[192 + lane];
        const float wx0 = Wih0[lane];       const float wx1 = Wih0[64 + lane];
        const float wx2 = Wih0[128 + lane]; const float wx3 = Wih0[192 + lane];
        float cst = c0in[b * HD + lane];
        h0ring[NS - 1][lane] = (_Float16)h0in[b * HD + lane];
        const float* xrow = x + (size_t)b * T;
        __syncthreads();

        for (int p = 0; p < nphase; ++p) {
            const int t0 = p * KP;
            if (t0 < T) {
                #pragma unroll 1
                for (int k = 0; k < KP; ++k) {
                    const int t = t0 + k;
                    if (t >= T) break;
                    const float xv = xrow[t];                   // uniform scalar load
                    const h8* hp = (const h8*)h0ring[(t + NS - 1) & (NS - 1)];
                    float a00 = b0, a01 = 0.f, a10 = b1, a11 = 0.f;
                    float a20 = b2, a21 = 0.f, a30 = b3, a31 = 0.f;
                    DOT4(hp);
                    const float ai = fmaf(wx0, xv, a00 + a01);
                    const float af = fmaf(wx1, xv, a10 + a11);
                    const float ag = fmaf(wx2, xv, a20 + a21);
                    const float ao = fmaf(wx3, xv, a30 + a31);
                    const float iv = fsig(ai), fv = fsig(af);
                    const float gv = ftanh_fast(ag), ov = fsig(ao);
                    cst = fmaf(fv, cst, iv * gv);
                    const float h = ov * ftanh_fast(cst);
                    h0ring[t & (NS - 1)][lane] = (_Float16)h;   // same-wave roundtrip
                }
            }
            __syncthreads();
        }
    } else if (wave == 1) {
        // ================= C: layer-1 recurrence (lag 2 phases) =================
        v2h wg0[32], wg1[32], wg2[32], wg3[32];
        LOADROW(Whh1, lane,        wg0);
        LOADROW(Whh1, 64 + lane,   wg1);
        LOADROW(Whh1, 128 + lane,  wg2);
        LOADROW(Whh1, 192 + lane,  wg3);
        float cst = c0in[B * HD + b * HD + lane];
        h1ring[NS - 1][lane] = (_Float16)h0in[B * HD + b * HD + lane];
        __syncthreads();

        for (int p = 0; p < nphase; ++p) {
            const int t0 = (p - 2) * KP;
            if (p >= 2 && t0 < T) {
                #pragma unroll 1
                for (int k = 0; k < KP; ++k) {
                    const int t = t0 + k;
                    if (t >= T) break;
                    const int s = t & (NS - 1);
                    const float x0 = xpring[s][0][lane];        // issued early,
                    const float x1 = xpring[s][1][lane];        // consumed after dots
                    const float x2 = xpring[s][2][lane];
                    const float x3 = xpring[s][3][lane];
                    const h8* hp = (const h8*)h1ring[(t + NS - 1) & (NS - 1)];
                    float a00 = 0.f, a01 = 0.f, a10 = 0.f, a11 = 0.f;
                    float a20 = 0.f, a21 = 0.f, a30 = 0.f, a31 = 0.f;
                    DOT4(hp);
                    const float ai = x0 + a00 + a01;
                    const float af = x1 + a10 + a11;
                    const float ag = x2 + a20 + a21;
                    const float ao = x3 + a30 + a31;
                    const float iv = fsig(ai), fv = fsig(af);
                    const float gv = ftanh_fast(ag), ov = fsig(ao);
                    cst = fmaf(fv, cst, iv * gv);
                    const float h = ov * ftanh_fast(cst);
                    h1ring[s][lane] = (_Float16)h;
                    h1f32[s][lane]  = h;                        // f32 h for output head
                }
            }
            __syncthreads();
        }
    } else if (wave <= 3) {
        // ================= B0/B1: layer-1 input projection (lag 1 phase) =========
        v2h wg0[32], wg1[32];
        const int g0 = (wave - 2) * 2;
        LOADROW(Wih1, g0 * HD + lane,       wg0);
        LOADROW(Wih1, (g0 + 1) * HD + lane, wg1);
        const float b0 = bih1[g0 * HD + lane]       + bhh1[g0 * HD + lane];
        const float b1 = bih1[(g0 + 1) * HD + lane] + bhh1[(g0 + 1) * HD + lane];
        __syncthreads();

        for (int p = 0; p < nphase; ++p) {
            const int t0 = (p - 1) * KP;
            if (p >= 1 && t0 < T) {
                #pragma unroll 1
                for (int k = 0; k < KP; ++k) {
                    const int t = t0 + k;
                    if (t >= T) break;
                    const int s = t & (NS - 1);
                    const h8* hp = (const h8*)h0ring[s];
                    float a00 = b0, a01 = 0.f, a10 = b1, a11 = 0.f;
                    #pragma unroll
                    for (int q = 0; q < 8; ++q) {
                        h8 hv = hp[q];
                        v2h p0 = {hv[0],hv[1]}, p1 = {hv[2],hv[3]};
                        v2h p2 = {hv[4],hv[5]}, p3 = {hv[6],hv[7]};
                        a00 = FDOT2(wg0[4*q+0], p0, a00); a01 = FDOT2(wg0[4*q+1], p1, a01);
                        a00 = FDOT2(wg0[4*q+2], p2, a00); a01 = FDOT2(wg0[4*q+3], p3, a01);
                        a10 = FDOT2(wg1[4*q+0], p0, a10); a11 = FDOT2(wg1[4*q+1], p1, a11);
                        a10 = FDOT2(wg1[4*q+2], p2, a10); a11 = FDOT2(wg1[4*q+3], p3, a11);
                    }
                    xpring[s][g0][lane]     = a00 + a01;
                    xpring[s][g0 + 1][lane] = a10 + a11;
                }
            }
            __syncthreads();
        }
    } else {
        // ================= D: output head (lag 3 phases) =================
        const float blin0 = blin[0];
        __syncthreads();

        for (int p = 0; p < nphase; ++p) {
            const int t0 = (p - 3) * KP;
            if (p >= 3 && t0 < T && lane < KP) {
                const int t = t0 + lane;
                if (t < T) {
                    const float4* hv4 = (const float4*)h1f32[t & (NS - 1)];
                    const float4* wp  = (const float4*)Wlin;
                    float acc = blin0;
                    #pragma unroll
                    for (int q = 0; q < 16; ++q) {
                        const float4 hv = hv4[q];
                        const float4 wv = wp[q];
                        acc = fmaf(wv.x, hv.x, acc);
                        acc = fmaf(wv.y, hv.y, acc);
                        acc = fmaf(wv.z, hv.z, acc);
                        acc = fmaf(wv.w, hv.w, acc);
                    }
                    out[(size_t)b * T + t] = acc;
                }
            }
            __syncthreads();
        }
    }
}

extern "C" void kernel_launch(void* const* d_in, const int* in_sizes, int n_in,
                              void* d_out, int out_size, void* d_ws, size_t ws_size,
                              hipStream_t stream)
{
    const float* x    = (const float*)d_in[0];
    const float* h0   = (const float*)d_in[1];
    const float* c0   = (const float*)d_in[2];
    const float* Wih0 = (const float*)d_in[3];
    const float* Whh0 = (const float*)d_in[4];
    const float* bih0 = (const float*)d_in[5];
    const float* bhh0 = (const float*)d_in[6];
    const float* Wih1 = (const float*)d_in[7];
    const float* Whh1 = (const float*)d_in[8];
    const float* bih1 = (const float*)d_in[9];
    const float* bhh1 = (const float*)d_in[10];
    const float* Wlin = (const float*)d_in[11];
    const float* blin = (const float*)d_in[12];
    float* out = (float*)d_out;

    const int B = in_sizes[1] / (2 * HD);   // h0 is [2,B,HD]
    const int T = in_sizes[0] / B;          // input is [B,T]

    lstm2_kernel<<<dim3(B), dim3(320), 0, stream>>>(
        x, h0, c0, Wih0, Whh0, bih0, bhh0,
        Wih1, Whh1, bih1, bhh1, Wlin, blin, out, B, T);
}